// Round 1
// baseline (489.504 us; speedup 1.0000x reference)
//
#include <hip/hip_runtime.h>
#include <hip/hip_bf16.h>

// Problem constants (LightConeAttention): B=2, T=6, H=16, W=16, C=256, NUM_HEADS=8
#define BB   2
#define TT   6
#define HH   16
#define WW   16
#define CC   256
#define NH   8
#define HD   32
#define NN   (TT*HH*WW)      // 1536
#define BN   (BB*NN)         // 3072
#define SCALE 0.17677669529663687f  // 1/sqrt(32)

// ---------------------------------------------------------------------------
// Simple fp32 tiled GEMM: C[M,N] = A[M,K] @ B[K,N] (+ bias). 64x64 tile, 4x4/thread.
// M,N multiples of 64; K multiple of 16 (all true here).
// ---------------------------------------------------------------------------
template<bool BIAS>
__global__ __launch_bounds__(256) void gemm_f32(const float* __restrict__ A,
                                                const float* __restrict__ Bm,
                                                const float* __restrict__ bias,
                                                float* __restrict__ Cm,
                                                int M, int Nn, int K) {
    __shared__ float As[16][65];
    __shared__ float Bs[16][65];
    const int tid = threadIdx.x;
    const int tx = tid & 15, ty = tid >> 4;
    const int m0 = blockIdx.y * 64, n0 = blockIdx.x * 64;
    float c[4][4] = {};
    for (int k0 = 0; k0 < K; k0 += 16) {
        #pragma unroll
        for (int i = 0; i < 4; ++i) {       // A tile 64 rows x 16 k
            int idx = tid + i * 256;
            int ml = idx >> 4, kk = idx & 15;
            As[kk][ml] = A[(size_t)(m0 + ml) * K + k0 + kk];
        }
        #pragma unroll
        for (int i = 0; i < 4; ++i) {       // B tile 16 k x 64 cols
            int idx = tid + i * 256;
            int kk = idx >> 6, nl = idx & 63;
            Bs[kk][nl] = Bm[(size_t)(k0 + kk) * Nn + n0 + nl];
        }
        __syncthreads();
        #pragma unroll
        for (int kk = 0; kk < 16; ++kk) {
            float a[4], bb[4];
            #pragma unroll
            for (int i = 0; i < 4; ++i) a[i] = As[kk][ty * 4 + i];
            #pragma unroll
            for (int j = 0; j < 4; ++j) bb[j] = Bs[kk][tx * 4 + j];
            #pragma unroll
            for (int i = 0; i < 4; ++i)
                #pragma unroll
                for (int j = 0; j < 4; ++j)
                    c[i][j] += a[i] * bb[j];
        }
        __syncthreads();
    }
    #pragma unroll
    for (int i = 0; i < 4; ++i) {
        int mrow = m0 + ty * 4 + i;
        #pragma unroll
        for (int j = 0; j < 4; ++j) {
            int ncol = n0 + tx * 4 + j;
            float v = c[i][j];
            if (BIAS) v += bias[ncol];
            Cm[(size_t)mrow * Nn + ncol] = v;
        }
    }
}

// ---------------------------------------------------------------------------
// Light-cone masked attention, fp32, one wave (64 lanes) per query row.
// Lanes stride over keys; per-lane online softmax; 6-step butterfly merge.
// qkv layout: [B*N, 3, NH, HD] row-major (stride 768 per row).
// attn_out layout: [B*N, NH*HD] = [B, N, C].
// ---------------------------------------------------------------------------
__global__ __launch_bounds__(256) void attn_kernel(const float* __restrict__ qkv,
                                                   float* __restrict__ attn_out) {
    const int wave = (int)((blockIdx.x * blockDim.x + threadIdx.x) >> 6);
    const int lane = threadIdx.x & 63;
    const int q_idx = wave % NN;
    const int bh    = wave / NN;
    const int h     = bh % NH;
    const int b     = bh / NH;
    const int tq = q_idx >> 8;
    const int hq = (q_idx >> 4) & 15;
    const int wq = q_idx & 15;

    const float* qrow = qkv + (size_t)(b * NN + q_idx) * (3 * CC) + h * HD;
    float qv[HD];
    #pragma unroll
    for (int d = 0; d < HD; ++d) qv[d] = qrow[d];

    float m = -1e30f, l = 0.f;
    float acc[HD];
    #pragma unroll
    for (int d = 0; d < HD; ++d) acc[d] = 0.f;

    const int kmax = (tq + 1) << 8;   // only keys with tk <= tq can be visible
    const int tqm  = (tq > 0) ? tq : 1;

    for (int k = lane; k < kmax; k += 64) {
        const int tk = k >> 8;
        const int hk = (k >> 4) & 15;
        const int wk = k & 15;
        const int r  = 1 + (15 * (tq - tk)) / tqm;   // exact vs reference floor
        const int dh = hk > hq ? hk - hq : hq - hk;
        const int dw = wk > wq ? wk - wq : wq - wk;
        if (dh <= r && dw <= r) {
            const float* krow = qkv + (size_t)(b * NN + k) * (3 * CC) + CC + h * HD;
            float s = 0.f;
            #pragma unroll
            for (int d = 0; d < HD; ++d) s += qv[d] * krow[d];
            s *= SCALE;
            const float mn   = fmaxf(m, s);
            const float corr = __expf(m - mn);
            const float p    = __expf(s - mn);
            l = l * corr + p;
            const float* vrow = krow + CC;
            #pragma unroll
            for (int d = 0; d < HD; ++d) acc[d] = acc[d] * corr + p * vrow[d];
            m = mn;
        }
    }

    // merge 64 per-lane partial softmaxes
    #pragma unroll
    for (int off = 1; off < 64; off <<= 1) {
        const float m2 = __shfl_xor(m, off);
        const float l2 = __shfl_xor(l, off);
        const float mn = fmaxf(m, m2);
        const float c1 = __expf(m - mn);
        const float c2 = __expf(m2 - mn);
        l = l * c1 + l2 * c2;
        #pragma unroll
        for (int d = 0; d < HD; ++d)
            acc[d] = acc[d] * c1 + __shfl_xor(acc[d], off) * c2;
        m = mn;
    }
    const float inv = 1.f / l;
    float* orow = attn_out + (size_t)(b * NN + q_idx) * CC + h * HD;
    #pragma unroll
    for (int d = 0; d < HD; ++d) {
        if (lane == d) orow[d] = acc[d] * inv;
    }
}

// ---------------------------------------------------------------------------
extern "C" void kernel_launch(void* const* d_in, const int* in_sizes, int n_in,
                              void* d_out, int out_size, void* d_ws, size_t ws_size,
                              hipStream_t stream) {
    const float* x    = (const float*)d_in[0];   // [B,T,H,W,C] = [3072,256]
    const float* Wqkv = (const float*)d_in[1];   // [256,768]
    const float* Wo   = (const float*)d_in[2];   // [256,256]
    const float* bo   = (const float*)d_in[3];   // [256]
    float* out = (float*)d_out;                  // [3072,256]

    float* qkv      = (float*)d_ws;              // [3072,768]  9.4 MB
    float* attn_out = qkv + (size_t)BN * 3 * CC; // [3072,256]  3.1 MB

    // 1) QKV projection: [3072,256] @ [256,768]
    {
        dim3 grid(3 * CC / 64, BN / 64);  // (12, 48)
        gemm_f32<false><<<grid, 256, 0, stream>>>(x, Wqkv, nullptr, qkv, BN, 3 * CC, CC);
    }
    // 2) masked attention: one wave per (b, h, q) row
    {
        int waves = BB * NH * NN;                // 24576
        dim3 grid(waves / 4);                    // 4 waves per 256-thread block
        attn_kernel<<<grid, 256, 0, stream>>>(qkv, attn_out);
    }
    // 3) output projection + bias: [3072,256] @ [256,256] + bo
    {
        dim3 grid(CC / 64, BN / 64);             // (4, 48)
        gemm_f32<true><<<grid, 256, 0, stream>>>(attn_out, Wo, bo, out, BN, CC, CC);
    }
}

// Round 2
// 112.858 us; speedup vs baseline: 4.3373x; 4.3373x over previous
//
#include <hip/hip_runtime.h>
#include <hip/hip_bf16.h>

// Problem constants (LightConeAttention): B=2, T=6, H=16, W=16, C=256, NUM_HEADS=8
#define BB   2
#define TT   6
#define HH   16
#define WW   16
#define CC   256
#define NH   8
#define HD   32
#define NN   (TT*HH*WW)      // 1536
#define BN   (BB*NN)         // 3072
#define SCALE 0.17677669529663687f  // 1/sqrt(32)

typedef __attribute__((ext_vector_type(8))) short bf16x8;
typedef __attribute__((ext_vector_type(4))) short bf16x4;
typedef __attribute__((ext_vector_type(4))) float f32x4;

static __device__ inline short f2bf(float x) {  // RNE float->bf16 bits
    unsigned u = __builtin_bit_cast(unsigned, x);
    unsigned r = (u + 0x7FFFu + ((u >> 16) & 1u)) >> 16;
    return (short)r;
}

static __device__ inline f32x4 mfma16x16x16_bf16(bf16x4 a, bf16x4 b, f32x4 c) {
#if __has_builtin(__builtin_amdgcn_mfma_f32_16x16x16bf16_1k)
    return __builtin_amdgcn_mfma_f32_16x16x16bf16_1k(a, b, c, 0, 0, 0);
#else
    // hazard cover: VALU-write -> MFMA-read needs a couple cycles
    asm volatile("s_nop 1\n\tv_mfma_f32_16x16x16_bf16 %0, %1, %2, %0"
                 : "+v"(c) : "v"(a), "v"(b));
    return c;
#endif
}

// ---------------------------------------------------------------------------
// fp32 tiled GEMM (unchanged from R1): C[M,N] = A[M,K] @ B[K,N] (+ bias).
// ---------------------------------------------------------------------------
template<bool BIAS>
__global__ __launch_bounds__(256) void gemm_f32(const float* __restrict__ A,
                                                const float* __restrict__ Bm,
                                                const float* __restrict__ bias,
                                                float* __restrict__ Cm,
                                                int M, int Nn, int K) {
    __shared__ float As[16][65];
    __shared__ float Bs[16][65];
    const int tid = threadIdx.x;
    const int tx = tid & 15, ty = tid >> 4;
    const int m0 = blockIdx.y * 64, n0 = blockIdx.x * 64;
    float c[4][4] = {};
    for (int k0 = 0; k0 < K; k0 += 16) {
        #pragma unroll
        for (int i = 0; i < 4; ++i) {
            int idx = tid + i * 256;
            int ml = idx >> 4, kk = idx & 15;
            As[kk][ml] = A[(size_t)(m0 + ml) * K + k0 + kk];
        }
        #pragma unroll
        for (int i = 0; i < 4; ++i) {
            int idx = tid + i * 256;
            int kk = idx >> 6, nl = idx & 63;
            Bs[kk][nl] = Bm[(size_t)(k0 + kk) * Nn + n0 + nl];
        }
        __syncthreads();
        #pragma unroll
        for (int kk = 0; kk < 16; ++kk) {
            float a[4], bb[4];
            #pragma unroll
            for (int i = 0; i < 4; ++i) a[i] = As[kk][ty * 4 + i];
            #pragma unroll
            for (int j = 0; j < 4; ++j) bb[j] = Bs[kk][tx * 4 + j];
            #pragma unroll
            for (int i = 0; i < 4; ++i)
                #pragma unroll
                for (int j = 0; j < 4; ++j)
                    c[i][j] += a[i] * bb[j];
        }
        __syncthreads();
    }
    #pragma unroll
    for (int i = 0; i < 4; ++i) {
        int mrow = m0 + ty * 4 + i;
        #pragma unroll
        for (int j = 0; j < 4; ++j) {
            int ncol = n0 + tx * 4 + j;
            float v = c[i][j];
            if (BIAS) v += bias[ncol];
            Cm[(size_t)mrow * Nn + ncol] = v;
        }
    }
}

// ---------------------------------------------------------------------------
// Pack K (bf16, [bh][n][32] row-major). Thread handles 8 d-elems; coalesced.
// ---------------------------------------------------------------------------
__global__ __launch_bounds__(256) void pack_k(const float* __restrict__ qkv,
                                              short* __restrict__ Kb) {
    int idx = blockIdx.x * 256 + threadIdx.x;       // 98304 total
    int d8 = idx & 3;
    int n  = (idx >> 2) % NN;
    int bh = (idx >> 2) / NN;
    int b = bh >> 3, h = bh & 7;
    const float* src = qkv + (size_t)(b * NN + n) * 768 + CC + h * 32 + d8 * 8;
    short tmp[8];
    #pragma unroll
    for (int i = 0; i < 8; ++i) tmp[i] = f2bf(src[i]);
    bf16x8* dst = (bf16x8*)(Kb + ((size_t)bh * NN + n) * 32 + d8 * 8);
    *dst = *(bf16x8*)tmp;
}

// ---------------------------------------------------------------------------
// Pack V^T (bf16, [bh][d=32][n=1536]). Gather reads (L2-resident), coalesced writes.
// ---------------------------------------------------------------------------
__global__ __launch_bounds__(256) void pack_vt(const float* __restrict__ qkv,
                                               short* __restrict__ VT) {
    int idx = blockIdx.x * 256 + threadIdx.x;       // 196608 total
    int n4 = (idx % 384) * 4;
    int d  = (idx / 384) % 32;
    int bh = idx / (384 * 32);
    int b = bh >> 3, h = bh & 7;
    short tmp[4];
    #pragma unroll
    for (int j = 0; j < 4; ++j) {
        tmp[j] = f2bf(qkv[(size_t)(b * NN + n4 + j) * 768 + 2 * CC + h * 32 + d]);
    }
    bf16x4* dst = (bf16x4*)(VT + ((size_t)bh * 32 + d) * NN + n4);
    *dst = *(bf16x4*)tmp;
}

// ---------------------------------------------------------------------------
// MFMA light-cone attention. One wave per (b,h,tq,hq) query row (16 queries).
// Swapped QK^T: S^T = mfma_16x16x32(A=K_tile, B=Q^T). Lane (g=lane>>4, q=lane&15)
// holds S[q][kw=4g+r]. Softmax per q: 4 in-lane + shfl_xor(16,32).
// P^T per-lane layout == B-fragment of mfma_16x16x16 -> PV with zero shuffles:
// O^T = mfma_16x16x16(A=V^T chunk, B=P). Tile-level light-cone sparsity.
// ---------------------------------------------------------------------------
__global__ __launch_bounds__(64) void attn_mfma(const float* __restrict__ qkv,
                                                const short* __restrict__ Kb,
                                                const short* __restrict__ VT,
                                                float* __restrict__ attn_out) {
    const int lane = threadIdx.x;
    const int g = lane >> 4, c16 = lane & 15;   // c16: query-w (B/D cols), key-w (A rows)
    const int wid = blockIdx.x;                 // 0..1535
    const int qrow = wid % 96;
    const int bh   = wid / 96;
    const int tq = qrow >> 4, hq = qrow & 15;
    const int b = bh >> 3, h = bh & 7;

    // Q fragment: B[d][q]: lane holds Q[q=c16][d=8g+i], fp32 -> bf16
    const int qn = tq * 256 + hq * 16 + c16;
    const float* qp = qkv + (size_t)(b * NN + qn) * 768 + h * 32 + g * 8;
    short qtmp[8];
    #pragma unroll
    for (int i = 0; i < 8; ++i) qtmp[i] = f2bf(qp[i]);
    bf16x8 qf = *(bf16x8*)qtmp;

    // |kw - wq| per reg (kw = 4g+r is this lane's D-row, wq = c16 is D-col)
    int dwv[4];
    #pragma unroll
    for (int r = 0; r < 4; ++r) {
        int d = 4 * g + r - c16;
        dwv[r] = d < 0 ? -d : d;
    }

    const short* KbBH = Kb + (size_t)bh * NN * 32;
    const short* VTBH = VT + (size_t)bh * 32 * NN;

    float m_run = -1e30f, l_run = 0.f;
    f32x4 acc0 = {0.f, 0.f, 0.f, 0.f};
    f32x4 acc1 = {0.f, 0.f, 0.f, 0.f};
    const f32x4 zf = {0.f, 0.f, 0.f, 0.f};
    const int tqm = tq ? tq : 1;

    for (int tk = 0; tk <= tq; ++tk) {
        const int rt = 1 + (15 * (tq - tk)) / tqm;   // exact vs reference floor
        int hk0 = hq - rt; if (hk0 < 0) hk0 = 0;
        int hk1 = hq + rt; if (hk1 > 15) hk1 = 15;
        for (int hk = hk0; hk <= hk1; ++hk) {
            const int kb = tk * 256 + hk * 16;
            // K fragment: A[kw=c16][d=8g+i]
            bf16x8 kf = *(const bf16x8*)(KbBH + (size_t)(kb + c16) * 32 + g * 8);
            f32x4 s = __builtin_amdgcn_mfma_f32_16x16x32_bf16(kf, qf, zf, 0, 0, 0);
            // scale + per-element w-window mask
            #pragma unroll
            for (int r = 0; r < 4; ++r) {
                float sv = s[r] * SCALE;
                s[r] = (dwv[r] <= rt) ? sv : -1e30f;
            }
            // online softmax (per query column)
            float tmax = fmaxf(fmaxf(s[0], s[1]), fmaxf(s[2], s[3]));
            tmax = fmaxf(tmax, __shfl_xor(tmax, 16));
            tmax = fmaxf(tmax, __shfl_xor(tmax, 32));
            const float mn = fmaxf(m_run, tmax);
            const float corr = __expf(m_run - mn);
            float p0 = __expf(s[0] - mn);
            float p1 = __expf(s[1] - mn);
            float p2 = __expf(s[2] - mn);
            float p3 = __expf(s[3] - mn);
            float ps = p0 + p1 + p2 + p3;
            ps += __shfl_xor(ps, 16);
            ps += __shfl_xor(ps, 32);
            l_run = l_run * corr + ps;
            m_run = mn;
            #pragma unroll
            for (int r = 0; r < 4; ++r) { acc0[r] *= corr; acc1[r] *= corr; }
            short ptmp[4] = { f2bf(p0), f2bf(p1), f2bf(p2), f2bf(p3) };
            bf16x4 pb = *(bf16x4*)ptmp;
            // V^T fragments: A[d'=c16][kw=4g+i], contiguous 8B reads
            bf16x4 v0 = *(const bf16x4*)(VTBH + (size_t)c16 * NN + kb + 4 * g);
            bf16x4 v1 = *(const bf16x4*)(VTBH + (size_t)(16 + c16) * NN + kb + 4 * g);
            acc0 = mfma16x16x16_bf16(v0, pb, acc0);
            acc1 = mfma16x16x16_bf16(v1, pb, acc1);
        }
    }
#if !__has_builtin(__builtin_amdgcn_mfma_f32_16x16x16bf16_1k)
    asm volatile("s_nop 7\n\ts_nop 7" :::);   // MFMA-write -> VALU-read hazard cover
#endif
    const float inv = 1.f / l_run;
    // lane (g,c16) holds O^T rows d' = 4g+r (+16 for acc1), col q = c16
    float* op = attn_out + (size_t)(b * NN + qn) * CC + h * 32;
    #pragma unroll
    for (int r = 0; r < 4; ++r) {
        op[4 * g + r]      = acc0[r] * inv;
        op[16 + 4 * g + r] = acc1[r] * inv;
    }
}

// ---------------------------------------------------------------------------
extern "C" void kernel_launch(void* const* d_in, const int* in_sizes, int n_in,
                              void* d_out, int out_size, void* d_ws, size_t ws_size,
                              hipStream_t stream) {
    const float* x    = (const float*)d_in[0];   // [3072,256]
    const float* Wqkv = (const float*)d_in[1];   // [256,768]
    const float* Wo   = (const float*)d_in[2];   // [256,256]
    const float* bo   = (const float*)d_in[3];   // [256]
    float* out = (float*)d_out;                  // [3072,256]

    float* qkv      = (float*)d_ws;                    // 3072*768 f32   (9.4 MB)
    float* attn_out = qkv + (size_t)BN * 3 * CC;       // 3072*256 f32   (3.1 MB)
    short* Kb       = (short*)(attn_out + (size_t)BN * CC);  // 16*1536*32 bf16 (1.5 MB)
    short* VT       = Kb + (size_t)16 * NN * 32;             // 16*32*1536 bf16 (1.5 MB)

    // 1) QKV projection
    {
        dim3 grid(3 * CC / 64, BN / 64);
        gemm_f32<false><<<grid, 256, 0, stream>>>(x, Wqkv, nullptr, qkv, BN, 3 * CC, CC);
    }
    // 2) pack K (bf16 row-major) and V^T (bf16 transposed)
    pack_k<<<384, 256, 0, stream>>>(qkv, Kb);
    pack_vt<<<768, 256, 0, stream>>>(qkv, VT);
    // 3) MFMA attention: one wave per query row
    attn_mfma<<<1536, 64, 0, stream>>>(qkv, Kb, VT, attn_out);
    // 4) output projection + bias
    {
        dim3 grid(CC / 64, BN / 64);
        gemm_f32<true><<<grid, 256, 0, stream>>>(attn_out, Wo, bo, out, BN, CC, CC);
    }
}

// Round 3
// 62.095 us; speedup vs baseline: 7.8831x; 1.8175x over previous
//
#include <hip/hip_runtime.h>
#include <hip/hip_bf16.h>

// Problem constants (LightConeAttention): B=2, T=6, H=16, W=16, C=256, NUM_HEADS=8
#define BB   2
#define TT   6
#define HH   16
#define WW   16
#define CC   256
#define NH   8
#define HD   32
#define NN   (TT*HH*WW)      // 1536
#define BN   (BB*NN)         // 3072
#define SCALE 0.17677669529663687f  // 1/sqrt(32)

typedef __attribute__((ext_vector_type(8))) short bf16x8;
typedef __attribute__((ext_vector_type(4))) short bf16x4;
typedef __attribute__((ext_vector_type(4))) float f32x4;

static __device__ inline short f2bf(float x) {  // RNE float->bf16 bits
    unsigned u = __builtin_bit_cast(unsigned, x);
    unsigned r = (u + 0x7FFFu + ((u >> 16) & 1u)) >> 16;
    return (short)r;
}

static __device__ inline f32x4 mfma16x16x16_bf16(bf16x4 a, bf16x4 b, f32x4 c) {
#if __has_builtin(__builtin_amdgcn_mfma_f32_16x16x16bf16_1k)
    return __builtin_amdgcn_mfma_f32_16x16x16bf16_1k(a, b, c, 0, 0, 0);
#else
    asm volatile("s_nop 1\n\tv_mfma_f32_16x16x16_bf16 %0, %1, %2, %0"
                 : "+v"(c) : "v"(a), "v"(b));
    return c;
#endif
}

// ---------------------------------------------------------------------------
// Pack inputs to bf16: x -> xb [3072][256]; Wqkv -> WqkvT [768][256] (transposed);
// Wo -> WoT [256][256] (transposed). One kernel, segmented by blockIdx.
// ---------------------------------------------------------------------------
__global__ __launch_bounds__(256) void pack_in(const float* __restrict__ x,
                                               const float* __restrict__ Wqkv,
                                               const float* __restrict__ Wo,
                                               short* __restrict__ xb,
                                               short* __restrict__ wqT,
                                               short* __restrict__ woT) {
    const int bid = blockIdx.x;
    if (bid < 384) {                       // x: 786432 elems, 8/thread, coalesced
        int i = (bid * 256 + threadIdx.x) * 8;
        short t[8];
        #pragma unroll
        for (int j = 0; j < 8; ++j) t[j] = f2bf(x[i + j]);
        *(bf16x8*)(xb + i) = *(bf16x8*)t;
    } else if (bid < 480) {                // WqkvT[n][k] = Wqkv[k][n]
        int idx = (bid - 384) * 256 + threadIdx.x;   // 24576 threads
        int k0 = (idx & 31) * 8;
        int n  = idx >> 5;                           // 0..767
        short t[8];
        #pragma unroll
        for (int j = 0; j < 8; ++j) t[j] = f2bf(Wqkv[(size_t)(k0 + j) * 768 + n]);
        *(bf16x8*)(wqT + (size_t)n * 256 + k0) = *(bf16x8*)t;
    } else {                               // WoT[n][k] = Wo[k][n]
        int idx = (bid - 480) * 256 + threadIdx.x;   // 8192 threads
        int k0 = (idx & 31) * 8;
        int n  = idx >> 5;                           // 0..255
        short t[8];
        #pragma unroll
        for (int j = 0; j < 8; ++j) t[j] = f2bf(Wo[(size_t)(k0 + j) * 256 + n]);
        *(bf16x8*)(woT + (size_t)n * 256 + k0) = *(bf16x8*)t;
    }
}

// ---------------------------------------------------------------------------
// GEMM1 (QKV projection), bf16 MFMA, no LDS (L2-resident operands).
// xb [3072][256] @ WqkvT[768][256]^T -> per-wave 32x64 tile, K=256 unrolled.
// Fused epilogue scatters into attention layouts:
//   Q,K -> [bh][n][32] bf16 ; V -> VT [bh][d][n] bf16 (transposed).
// grid (12, 24), block 256 (4 waves, each 32 rows).
// ---------------------------------------------------------------------------
__global__ __launch_bounds__(256) void gemm1_qkv(const short* __restrict__ xb,
                                                 const short* __restrict__ wqT,
                                                 short* __restrict__ Qb,
                                                 short* __restrict__ Kb,
                                                 short* __restrict__ VT) {
    const int w = threadIdx.x >> 6, lane = threadIdx.x & 63;
    const int g = lane >> 4, c16 = lane & 15;
    const int mw = blockIdx.y * 128 + w * 32;
    const int n0 = blockIdx.x * 64;
    f32x4 acc[2][4] = {};
    #pragma unroll
    for (int ks = 0; ks < 8; ++ks) {
        const int k0 = ks * 32;
        bf16x8 a0 = *(const bf16x8*)(xb + (size_t)(mw + c16) * 256 + k0 + g * 8);
        bf16x8 a1 = *(const bf16x8*)(xb + (size_t)(mw + 16 + c16) * 256 + k0 + g * 8);
        #pragma unroll
        for (int ni = 0; ni < 4; ++ni) {
            bf16x8 bfr = *(const bf16x8*)(wqT + (size_t)(n0 + ni * 16 + c16) * 256 + k0 + g * 8);
            acc[0][ni] = __builtin_amdgcn_mfma_f32_16x16x32_bf16(a0, bfr, acc[0][ni], 0, 0, 0);
            acc[1][ni] = __builtin_amdgcn_mfma_f32_16x16x32_bf16(a1, bfr, acc[1][ni], 0, 0, 0);
        }
    }
    // D layout: row m = mw + mi*16 + 4g + r (A index), col = n0 + ni*16 + c16 (B index)
    #pragma unroll
    for (int mi = 0; mi < 2; ++mi) {
        const int brow = mw + mi * 16;
        const int b = brow >= NN;
        const int nl0 = brow - b * NN + 4 * g;
        #pragma unroll
        for (int ni = 0; ni < 4; ++ni) {
            const int col = n0 + ni * 16;
            const int sec = col >> 8;
            const int h   = (col >> 5) & 7;
            const int d0  = col & 31;          // 0 or 16
            const int bh  = b * 8 + h;
            #pragma unroll
            for (int r = 0; r < 4; ++r) {
                const short v = f2bf(acc[mi][ni][r]);
                const int nl = nl0 + r;
                if (sec == 0)      Qb[((size_t)bh * NN + nl) * 32 + d0 + c16] = v;
                else if (sec == 1) Kb[((size_t)bh * NN + nl) * 32 + d0 + c16] = v;
                else               VT[((size_t)bh * 32 + d0 + c16) * NN + nl] = v;
            }
        }
    }
}

// ---------------------------------------------------------------------------
// MFMA light-cone attention. One BLOCK (4 waves) per (b,h,tq,hq) query row.
// Visible 16-key tiles enumerated via packed compare-select; waves take tiles
// round-robin (t = w, w+4, ...) with next-tile K/V prefetch; per-wave online
// softmax; 4-way merge via LDS at the end.
// ---------------------------------------------------------------------------
__global__ __launch_bounds__(256) void attn_mfma(const short* __restrict__ Qb,
                                                 const short* __restrict__ Kb,
                                                 const short* __restrict__ VT,
                                                 short* __restrict__ attn_out) {
    const int w    = threadIdx.x >> 6;
    const int lane = threadIdx.x & 63;
    const int g = lane >> 4, c16 = lane & 15;
    const int wid  = blockIdx.x;            // 0..1535
    const int qrow = wid % 96;
    const int bh   = wid / 96;
    const int tq = qrow >> 4, hq = qrow & 15;

    const int qn = tq * 256 + hq * 16 + c16;
    const bf16x8 qf = *(const bf16x8*)(Qb + ((size_t)bh * NN + qn) * 32 + g * 8);

    int dwv[4];
    #pragma unroll
    for (int r = 0; r < 4; ++r) { int d = 4 * g + r - c16; dwv[r] = d < 0 ? -d : d; }

    // enumerate visible (tk,hk) tiles: pk[tk] = (cstart<<16)|(tk<<12)|(h0<<8)|rt
    const int tqm = tq ? tq : 1;
    int ntiles = 0;
    int pk[6];
    #pragma unroll
    for (int tk = 0; tk < 6; ++tk) {
        int rt = 1 + (15 * (tq - tk)) / tqm;
        int h0 = hq - rt; if (h0 < 0) h0 = 0;
        int h1 = hq + rt; if (h1 > 15) h1 = 15;
        int cnt = (tk <= tq) ? (h1 - h0 + 1) : 0;
        pk[tk] = (ntiles << 16) | (tk << 12) | (h0 << 8) | (rt & 255);
        ntiles += cnt;
    }
    auto lookup = [&](int t, int& kb, int& rt) {
        int sel = pk[0];
        #pragma unroll
        for (int k = 1; k < 6; ++k)
            if (t >= (pk[k] >> 16)) sel = pk[k];
        const int tk = (sel >> 12) & 15;
        const int h0 = (sel >> 8) & 15;
        rt = sel & 255;
        const int hk = h0 + (t - (sel >> 16));
        kb = tk * 256 + hk * 16;
    };

    const short* KbBH = Kb + (size_t)bh * NN * 32;
    const short* VTBH = VT + (size_t)bh * 32 * NN;

    float m_run = -1e30f, l_run = 0.f;
    f32x4 acc0 = {0.f, 0.f, 0.f, 0.f};
    f32x4 acc1 = {0.f, 0.f, 0.f, 0.f};
    const f32x4 zf = {0.f, 0.f, 0.f, 0.f};

    int t = w;
    int kb = 0, rt = 0;
    bf16x8 kf = {};
    bf16x4 v0 = {}, v1 = {};
    if (t < ntiles) {
        lookup(t, kb, rt);
        kf = *(const bf16x8*)(KbBH + (size_t)(kb + c16) * 32 + g * 8);
        v0 = *(const bf16x4*)(VTBH + (size_t)c16 * NN + kb + 4 * g);
        v1 = *(const bf16x4*)(VTBH + (size_t)(16 + c16) * NN + kb + 4 * g);
    }
    while (t < ntiles) {
        const int tn = t + 4;
        int kb2, rt2;
        bf16x8 kf2; bf16x4 v02, v12;
        if (tn < ntiles) {              // prefetch next tile (wave-uniform branch)
            lookup(tn, kb2, rt2);
            kf2 = *(const bf16x8*)(KbBH + (size_t)(kb2 + c16) * 32 + g * 8);
            v02 = *(const bf16x4*)(VTBH + (size_t)c16 * NN + kb2 + 4 * g);
            v12 = *(const bf16x4*)(VTBH + (size_t)(16 + c16) * NN + kb2 + 4 * g);
        } else { kb2 = kb; rt2 = rt; kf2 = kf; v02 = v0; v12 = v1; }

        f32x4 s = __builtin_amdgcn_mfma_f32_16x16x32_bf16(kf, qf, zf, 0, 0, 0);
        #pragma unroll
        for (int r = 0; r < 4; ++r) {
            const float sv = s[r] * SCALE;
            s[r] = (dwv[r] <= rt) ? sv : -1e30f;
        }
        float tmax = fmaxf(fmaxf(s[0], s[1]), fmaxf(s[2], s[3]));
        tmax = fmaxf(tmax, __shfl_xor(tmax, 16));
        tmax = fmaxf(tmax, __shfl_xor(tmax, 32));
        const float mn   = fmaxf(m_run, tmax);
        const float corr = __expf(m_run - mn);
        const float p0 = __expf(s[0] - mn);
        const float p1 = __expf(s[1] - mn);
        const float p2 = __expf(s[2] - mn);
        const float p3 = __expf(s[3] - mn);
        float ps = p0 + p1 + p2 + p3;
        ps += __shfl_xor(ps, 16);
        ps += __shfl_xor(ps, 32);
        l_run = l_run * corr + ps;
        m_run = mn;
        #pragma unroll
        for (int r = 0; r < 4; ++r) { acc0[r] *= corr; acc1[r] *= corr; }
        short ptmp[4] = { f2bf(p0), f2bf(p1), f2bf(p2), f2bf(p3) };
        const bf16x4 pb = *(bf16x4*)ptmp;
        acc0 = mfma16x16x16_bf16(v0, pb, acc0);
        acc1 = mfma16x16x16_bf16(v1, pb, acc1);

        t = tn; kb = kb2; rt = rt2; kf = kf2; v0 = v02; v1 = v12;
    }

    // 4-way online-softmax merge via LDS (padded: stride 9 -> conflict-free)
    __shared__ float sm_m[4][16];
    __shared__ float sm_l[4][16];
    __shared__ float sm_acc[4][64][9];
    if (g == 0) { sm_m[w][c16] = m_run; sm_l[w][c16] = l_run; }
    #pragma unroll
    for (int r = 0; r < 4; ++r) {
        sm_acc[w][lane][r]     = acc0[r];
        sm_acc[w][lane][4 + r] = acc1[r];
    }
    __syncthreads();
    if (w == 0) {
        const float m0 = sm_m[0][c16], m1 = sm_m[1][c16];
        const float m2 = sm_m[2][c16], m3 = sm_m[3][c16];
        const float mm = fmaxf(fmaxf(m0, m1), fmaxf(m2, m3));
        const float c0 = __expf(m0 - mm), c1 = __expf(m1 - mm);
        const float c2 = __expf(m2 - mm), c3 = __expf(m3 - mm);
        const float lt = sm_l[0][c16] * c0 + sm_l[1][c16] * c1
                       + sm_l[2][c16] * c2 + sm_l[3][c16] * c3;
        const float inv = 1.f / lt;
        short* op = attn_out + ((size_t)(bh >> 3) * NN + qn) * CC + (bh & 7) * 32;
        #pragma unroll
        for (int r = 0; r < 8; ++r) {
            const float a = sm_acc[0][lane][r] * c0 + sm_acc[1][lane][r] * c1
                          + sm_acc[2][lane][r] * c2 + sm_acc[3][lane][r] * c3;
            const int d = (r < 4) ? (4 * g + r) : (16 + 4 * g + (r - 4));
            op[d] = f2bf(a * inv);
        }
    }
}

// ---------------------------------------------------------------------------
// GEMM2 (output projection + bias), bf16 MFMA, fp32 out. grid (4, 24).
// ---------------------------------------------------------------------------
__global__ __launch_bounds__(256) void gemm2_out(const short* __restrict__ aob,
                                                 const short* __restrict__ woT,
                                                 const float* __restrict__ bias,
                                                 float* __restrict__ out) {
    const int w = threadIdx.x >> 6, lane = threadIdx.x & 63;
    const int g = lane >> 4, c16 = lane & 15;
    const int mw = blockIdx.y * 128 + w * 32;
    const int n0 = blockIdx.x * 64;
    f32x4 acc[2][4] = {};
    #pragma unroll
    for (int ks = 0; ks < 8; ++ks) {
        const int k0 = ks * 32;
        bf16x8 a0 = *(const bf16x8*)(aob + (size_t)(mw + c16) * 256 + k0 + g * 8);
        bf16x8 a1 = *(const bf16x8*)(aob + (size_t)(mw + 16 + c16) * 256 + k0 + g * 8);
        #pragma unroll
        for (int ni = 0; ni < 4; ++ni) {
            bf16x8 bfr = *(const bf16x8*)(woT + (size_t)(n0 + ni * 16 + c16) * 256 + k0 + g * 8);
            acc[0][ni] = __builtin_amdgcn_mfma_f32_16x16x32_bf16(a0, bfr, acc[0][ni], 0, 0, 0);
            acc[1][ni] = __builtin_amdgcn_mfma_f32_16x16x32_bf16(a1, bfr, acc[1][ni], 0, 0, 0);
        }
    }
    #pragma unroll
    for (int mi = 0; mi < 2; ++mi) {
        #pragma unroll
        for (int ni = 0; ni < 4; ++ni) {
            const int col = n0 + ni * 16 + c16;
            const float bv = bias[col];
            #pragma unroll
            for (int r = 0; r < 4; ++r)
                out[(size_t)(mw + mi * 16 + 4 * g + r) * 256 + col] = acc[mi][ni][r] + bv;
        }
    }
}

// ---------------------------------------------------------------------------
extern "C" void kernel_launch(void* const* d_in, const int* in_sizes, int n_in,
                              void* d_out, int out_size, void* d_ws, size_t ws_size,
                              hipStream_t stream) {
    const float* x    = (const float*)d_in[0];   // [3072,256]
    const float* Wqkv = (const float*)d_in[1];   // [256,768]
    const float* Wo   = (const float*)d_in[2];   // [256,256]
    const float* bo   = (const float*)d_in[3];   // [256]
    float* out = (float*)d_out;                  // [3072,256] fp32

    short* xb  = (short*)d_ws;                   // 786432
    short* wqT = xb  + 786432;                   // 196608
    short* woT = wqT + 196608;                   // 65536
    short* Qb  = woT + 65536;                    // 786432
    short* Kb  = Qb  + 786432;                   // 786432
    short* VT  = Kb  + 786432;                   // 786432
    short* aob = VT  + 786432;                   // 786432  (~8.4 MB total)

    pack_in<<<512, 256, 0, stream>>>(x, Wqkv, Wo, xb, wqT, woT);
    {
        dim3 grid(12, 24);
        gemm1_qkv<<<grid, 256, 0, stream>>>(xb, wqT, Qb, Kb, VT);
    }
    attn_mfma<<<1536, 256, 0, stream>>>(Qb, Kb, VT, aob);
    {
        dim3 grid(4, 24);
        gemm2_out<<<grid, 256, 0, stream>>>(aob, woT, bo, out);
    }
}

// Round 4
// 47.460 us; speedup vs baseline: 10.3139x; 1.3084x over previous
//
#include <hip/hip_runtime.h>
#include <hip/hip_bf16.h>

// Problem constants (LightConeAttention): B=2, T=6, H=16, W=16, C=256, NUM_HEADS=8
#define BB   2
#define TT   6
#define HH   16
#define WW   16
#define CC   256
#define NH   8
#define HD   32
#define NN   (TT*HH*WW)      // 1536
#define BN   (BB*NN)         // 3072
#define SCALE 0.17677669529663687f  // 1/sqrt(32)

typedef __attribute__((ext_vector_type(8))) short bf16x8;
typedef __attribute__((ext_vector_type(4))) short bf16x4;
typedef __attribute__((ext_vector_type(4))) float f32x4;

static __device__ inline short f2b(float x) {   // RNE via compiler (v_cvt_pk fusion)
    __hip_bfloat16 h = __float2bfloat16(x);
    return __builtin_bit_cast(short, h);
}

static __device__ inline f32x4 mfma16x16x16_bf16(bf16x4 a, bf16x4 b, f32x4 c) {
#if __has_builtin(__builtin_amdgcn_mfma_f32_16x16x16bf16_1k)
    return __builtin_amdgcn_mfma_f32_16x16x16bf16_1k(a, b, c, 0, 0, 0);
#else
    asm volatile("s_nop 1\n\tv_mfma_f32_16x16x16_bf16 %0, %1, %2, %0"
                 : "+v"(c) : "v"(a), "v"(b));
    return c;
#endif
}

// ---------------------------------------------------------------------------
// Pack inputs to bf16: x -> xb [3072][256]; Wqkv -> WqkvT [768][256]; Wo -> WoT.
// ---------------------------------------------------------------------------
__global__ __launch_bounds__(256) void pack_in(const float* __restrict__ x,
                                               const float* __restrict__ Wqkv,
                                               const float* __restrict__ Wo,
                                               short* __restrict__ xb,
                                               short* __restrict__ wqT,
                                               short* __restrict__ woT) {
    const int bid = blockIdx.x;
    if (bid < 384) {
        int i = (bid * 256 + threadIdx.x) * 8;
        short t[8];
        #pragma unroll
        for (int j = 0; j < 8; ++j) t[j] = f2b(x[i + j]);
        *(bf16x8*)(xb + i) = *(bf16x8*)t;
    } else if (bid < 480) {                // WqkvT[n][k] = Wqkv[k][n]
        int idx = (bid - 384) * 256 + threadIdx.x;
        int k0 = (idx & 31) * 8;
        int n  = idx >> 5;
        short t[8];
        #pragma unroll
        for (int j = 0; j < 8; ++j) t[j] = f2b(Wqkv[(size_t)(k0 + j) * 768 + n]);
        *(bf16x8*)(wqT + (size_t)n * 256 + k0) = *(bf16x8*)t;
    } else {                               // WoT[n][k] = Wo[k][n]
        int idx = (bid - 480) * 256 + threadIdx.x;
        int k0 = (idx & 31) * 8;
        int n  = idx >> 5;
        short t[8];
        #pragma unroll
        for (int j = 0; j < 8; ++j) t[j] = f2b(Wo[(size_t)(k0 + j) * 256 + n]);
        *(bf16x8*)(woT + (size_t)n * 256 + k0) = *(bf16x8*)t;
    }
}

// ---------------------------------------------------------------------------
// GEMM1 (QKV projection), bf16 MFMA, no LDS. Epilogue scatters to attention
// layouts: Q (pre-scaled by SCALE) and K -> [bh][n][32]; V -> V4 [bh][n>>2][d][n&3]
// (packed bf16x4 stores, fully dense). grid (12, 24), block 256.
// ---------------------------------------------------------------------------
__global__ __launch_bounds__(256) void gemm1_qkv(const short* __restrict__ xb,
                                                 const short* __restrict__ wqT,
                                                 short* __restrict__ Qb,
                                                 short* __restrict__ Kb,
                                                 short* __restrict__ V4) {
    const int w = threadIdx.x >> 6, lane = threadIdx.x & 63;
    const int g = lane >> 4, c16 = lane & 15;
    const int mw = blockIdx.y * 128 + w * 32;
    const int n0 = blockIdx.x * 64;
    f32x4 acc[2][4] = {};
    #pragma unroll
    for (int ks = 0; ks < 8; ++ks) {
        const int k0 = ks * 32;
        bf16x8 a0 = *(const bf16x8*)(xb + (size_t)(mw + c16) * 256 + k0 + g * 8);
        bf16x8 a1 = *(const bf16x8*)(xb + (size_t)(mw + 16 + c16) * 256 + k0 + g * 8);
        #pragma unroll
        for (int ni = 0; ni < 4; ++ni) {
            bf16x8 bfr = *(const bf16x8*)(wqT + (size_t)(n0 + ni * 16 + c16) * 256 + k0 + g * 8);
            acc[0][ni] = __builtin_amdgcn_mfma_f32_16x16x32_bf16(a0, bfr, acc[0][ni], 0, 0, 0);
            acc[1][ni] = __builtin_amdgcn_mfma_f32_16x16x32_bf16(a1, bfr, acc[1][ni], 0, 0, 0);
        }
    }
    const int sec = blockIdx.x >> 2;       // 0:Q 1:K 2:V (uniform per block)
    #pragma unroll
    for (int mi = 0; mi < 2; ++mi) {
        const int brow = mw + mi * 16;
        const int b = brow >= NN;
        const int nbase = brow - b * NN;   // multiple of 16
        #pragma unroll
        for (int ni = 0; ni < 4; ++ni) {
            const int col = n0 + ni * 16;
            const int h  = (col >> 5) & 7;
            const int d0 = col & 31;       // 0 or 16
            const int bh = b * 8 + h;
            if (sec == 2) {
                short t4[4];
                #pragma unroll
                for (int r = 0; r < 4; ++r) t4[r] = f2b(acc[mi][ni][r]);
                size_t off = ((size_t)(bh * 384 + (nbase >> 2) + g) * 32 + d0 + c16) * 4;
                *(bf16x4*)(V4 + off) = *(bf16x4*)t4;
            } else {
                short* dst = (sec == 0) ? Qb : Kb;
                const float sc = (sec == 0) ? SCALE : 1.f;
                #pragma unroll
                for (int r = 0; r < 4; ++r)
                    dst[((size_t)bh * NN + nbase + 4 * g + r) * 32 + d0 + c16] =
                        f2b(acc[mi][ni][r] * sc);
            }
        }
    }
}

// ---------------------------------------------------------------------------
// MFMA light-cone attention, pair-processed. One block (4 waves) per query row.
// Tile descs (kb<<8|rt) built once in LDS (sentinel rt=-1 pads to even).
// Per pair: 2 swapped-QK^T MFMAs, ONE combined mask/max/exp/softmax update,
// 4 PV MFMAs (V4 layout: contiguous 8B A-fragments). Defer-rescale via __all.
// ---------------------------------------------------------------------------
__global__ __launch_bounds__(256) void attn_mfma(const short* __restrict__ Qb,
                                                 const short* __restrict__ Kb,
                                                 const short* __restrict__ V4,
                                                 short* __restrict__ aob) {
    const int w    = threadIdx.x >> 6;
    const int lane = threadIdx.x & 63;
    const int g = lane >> 4, c16 = lane & 15;
    const int wid  = blockIdx.x;            // 0..1535
    const int qrow = wid % 96;
    const int bh   = wid / 96;
    const int tq = qrow >> 4, hq = qrow & 15;

    const int qn = tq * 256 + hq * 16 + c16;
    const bf16x8 qf = *(const bf16x8*)(Qb + ((size_t)bh * NN + qn) * 32 + g * 8);

    int dwv[4];
    #pragma unroll
    for (int r = 0; r < 4; ++r) { int d = 4 * g + r - c16; dwv[r] = d < 0 ? -d : d; }

    // per-thread row scan (registers, statically indexed)
    const int tqm = tq ? tq : 1;
    int cst[6], h0s[6], rtv[6];
    int ntiles = 0;
    #pragma unroll
    for (int tk = 0; tk < 6; ++tk) {
        int rt = 1 + (15 * (tq - tk)) / tqm;
        int h0 = hq - rt; h0 = h0 < 0 ? 0 : h0;
        int h1 = hq + rt; h1 = h1 > 15 ? 15 : h1;
        int cnt = (tk <= tq) ? (h1 - h0 + 1) : 0;
        cst[tk] = ntiles; h0s[tk] = h0; rtv[tk] = rt;
        ntiles += cnt;
    }

    __shared__ alignas(8) int desc[98];
    if (w == 0) {
        for (int t = lane; t < 98; t += 64) {
            int d = 255;                         // sentinel: kb=0, rt=-1
            if (t < ntiles) {
                int sel = 0;
                #pragma unroll
                for (int tk = 1; tk < 6; ++tk)
                    if (tk <= tq && t >= cst[tk]) sel = tk;
                const int hk = h0s[sel] + (t - cst[sel]);
                d = ((sel * 256 + hk * 16) << 8) | (rtv[sel] & 255);
            }
            desc[t] = d;
        }
    }
    __syncthreads();

    const short* KbBH = Kb + (size_t)bh * NN * 32;
    const short* V4BH = V4 + (size_t)bh * 384 * 32 * 4;

    float m_run = -1e30f, l_run = 0.f;
    f32x4 acc0 = {0.f, 0.f, 0.f, 0.f};
    f32x4 acc1 = {0.f, 0.f, 0.f, 0.f};
    const f32x4 zf = {0.f, 0.f, 0.f, 0.f};
    const int npairs = (ntiles + 1) >> 1;

    for (int pi = w; pi < npairs; pi += 4) {
        const int2 dd = *(const int2*)&desc[2 * pi];
        const int kba = dd.x >> 8, kbb = dd.y >> 8;
        const int rta = (dd.x << 24) >> 24, rtb = (dd.y << 24) >> 24;

        const bf16x8 kfa = *(const bf16x8*)(KbBH + (size_t)(kba + c16) * 32 + g * 8);
        const bf16x8 kfb = *(const bf16x8*)(KbBH + (size_t)(kbb + c16) * 32 + g * 8);
        const bf16x4 v0a = *(const bf16x4*)(V4BH + ((size_t)((kba >> 2) + g) * 32 + c16) * 4);
        const bf16x4 v1a = *(const bf16x4*)(V4BH + ((size_t)((kba >> 2) + g) * 32 + 16 + c16) * 4);
        const bf16x4 v0b = *(const bf16x4*)(V4BH + ((size_t)((kbb >> 2) + g) * 32 + c16) * 4);
        const bf16x4 v1b = *(const bf16x4*)(V4BH + ((size_t)((kbb >> 2) + g) * 32 + 16 + c16) * 4);

        f32x4 sa = __builtin_amdgcn_mfma_f32_16x16x32_bf16(kfa, qf, zf, 0, 0, 0);
        f32x4 sb = __builtin_amdgcn_mfma_f32_16x16x32_bf16(kfb, qf, zf, 0, 0, 0);

        float e[8];
        #pragma unroll
        for (int r = 0; r < 4; ++r) {
            e[r]     = (dwv[r] <= rta) ? sa[r] : -1e30f;
            e[4 + r] = (dwv[r] <= rtb) ? sb[r] : -1e30f;
        }
        float tmax = fmaxf(fmaxf(fmaxf(e[0], e[1]), fmaxf(e[2], e[3])),
                           fmaxf(fmaxf(e[4], e[5]), fmaxf(e[6], e[7])));
        tmax = fmaxf(tmax, __shfl_xor(tmax, 16));
        tmax = fmaxf(tmax, __shfl_xor(tmax, 32));

        if (!__all(tmax <= m_run)) {           // defer-rescale (wave-uniform)
            const float mn   = fmaxf(m_run, tmax);
            const float corr = __expf(m_run - mn);
            l_run *= corr;
            #pragma unroll
            for (int r = 0; r < 4; ++r) { acc0[r] *= corr; acc1[r] *= corr; }
            m_run = mn;
        }
        float p[8];
        #pragma unroll
        for (int i = 0; i < 8; ++i) p[i] = __expf(e[i] - m_run);
        float ps = ((p[0] + p[1]) + (p[2] + p[3])) + ((p[4] + p[5]) + (p[6] + p[7]));
        ps += __shfl_xor(ps, 16);
        ps += __shfl_xor(ps, 32);
        l_run += ps;

        short pa4[4], pb4[4];
        #pragma unroll
        for (int r = 0; r < 4; ++r) { pa4[r] = f2b(p[r]); pb4[r] = f2b(p[4 + r]); }
        const bf16x4 pav = *(bf16x4*)pa4;
        const bf16x4 pbv = *(bf16x4*)pb4;
        acc0 = mfma16x16x16_bf16(v0a, pav, acc0);
        acc1 = mfma16x16x16_bf16(v1a, pav, acc1);
        acc0 = mfma16x16x16_bf16(v0b, pbv, acc0);
        acc1 = mfma16x16x16_bf16(v1b, pbv, acc1);
    }

    // 4-way online-softmax merge via LDS
    __shared__ float sm_m[4][16];
    __shared__ float sm_l[4][16];
    __shared__ float sm_acc[4][64][9];
    if (g == 0) { sm_m[w][c16] = m_run; sm_l[w][c16] = l_run; }
    #pragma unroll
    for (int r = 0; r < 4; ++r) {
        sm_acc[w][lane][r]     = acc0[r];
        sm_acc[w][lane][4 + r] = acc1[r];
    }
    __syncthreads();
    if (w == 0) {
        const float m0 = sm_m[0][c16], m1 = sm_m[1][c16];
        const float m2 = sm_m[2][c16], m3 = sm_m[3][c16];
        const float mm = fmaxf(fmaxf(m0, m1), fmaxf(m2, m3));
        const float c0 = __expf(m0 - mm), c1 = __expf(m1 - mm);
        const float c2 = __expf(m2 - mm), c3 = __expf(m3 - mm);
        const float lt = sm_l[0][c16] * c0 + sm_l[1][c16] * c1
                       + sm_l[2][c16] * c2 + sm_l[3][c16] * c3;
        const float inv = 1.f / lt;
        short* op = aob + ((size_t)(bh >> 3) * NN + qn) * CC + (bh & 7) * 32;
        short t0[4], t1[4];
        #pragma unroll
        for (int r = 0; r < 4; ++r) {
            const float a0 = sm_acc[0][lane][r] * c0 + sm_acc[1][lane][r] * c1
                           + sm_acc[2][lane][r] * c2 + sm_acc[3][lane][r] * c3;
            const float a1 = sm_acc[0][lane][4 + r] * c0 + sm_acc[1][lane][4 + r] * c1
                           + sm_acc[2][lane][4 + r] * c2 + sm_acc[3][lane][4 + r] * c3;
            t0[r] = f2b(a0 * inv);
            t1[r] = f2b(a1 * inv);
        }
        *(bf16x4*)(op + 4 * g)      = *(bf16x4*)t0;   // d = 4g+0..3
        *(bf16x4*)(op + 16 + 4 * g) = *(bf16x4*)t1;   // d = 16+4g+0..3
    }
}

// ---------------------------------------------------------------------------
// GEMM2 (output projection + bias), bf16 MFMA, fp32 out. grid (4, 24).
// ---------------------------------------------------------------------------
__global__ __launch_bounds__(256) void gemm2_out(const short* __restrict__ aob,
                                                 const short* __restrict__ woT,
                                                 const float* __restrict__ bias,
                                                 float* __restrict__ out) {
    const int w = threadIdx.x >> 6, lane = threadIdx.x & 63;
    const int g = lane >> 4, c16 = lane & 15;
    const int mw = blockIdx.y * 128 + w * 32;
    const int n0 = blockIdx.x * 64;
    f32x4 acc[2][4] = {};
    #pragma unroll
    for (int ks = 0; ks < 8; ++ks) {
        const int k0 = ks * 32;
        bf16x8 a0 = *(const bf16x8*)(aob + (size_t)(mw + c16) * 256 + k0 + g * 8);
        bf16x8 a1 = *(const bf16x8*)(aob + (size_t)(mw + 16 + c16) * 256 + k0 + g * 8);
        #pragma unroll
        for (int ni = 0; ni < 4; ++ni) {
            bf16x8 bfr = *(const bf16x8*)(woT + (size_t)(n0 + ni * 16 + c16) * 256 + k0 + g * 8);
            acc[0][ni] = __builtin_amdgcn_mfma_f32_16x16x32_bf16(a0, bfr, acc[0][ni], 0, 0, 0);
            acc[1][ni] = __builtin_amdgcn_mfma_f32_16x16x32_bf16(a1, bfr, acc[1][ni], 0, 0, 0);
        }
    }
    #pragma unroll
    for (int mi = 0; mi < 2; ++mi) {
        #pragma unroll
        for (int ni = 0; ni < 4; ++ni) {
            const int col = n0 + ni * 16 + c16;
            const float bv = bias[col];
            #pragma unroll
            for (int r = 0; r < 4; ++r)
                out[(size_t)(mw + mi * 16 + 4 * g + r) * 256 + col] = acc[mi][ni][r] + bv;
        }
    }
}

// ---------------------------------------------------------------------------
extern "C" void kernel_launch(void* const* d_in, const int* in_sizes, int n_in,
                              void* d_out, int out_size, void* d_ws, size_t ws_size,
                              hipStream_t stream) {
    const float* x    = (const float*)d_in[0];
    const float* Wqkv = (const float*)d_in[1];
    const float* Wo   = (const float*)d_in[2];
    const float* bo   = (const float*)d_in[3];
    float* out = (float*)d_out;

    short* xb  = (short*)d_ws;                   // 786432
    short* wqT = xb  + 786432;                   // 196608
    short* woT = wqT + 196608;                   // 65536
    short* Qb  = woT + 65536;                    // 786432
    short* Kb  = Qb  + 786432;                   // 786432
    short* V4  = Kb  + 786432;                   // 786432 ([bh][n>>2][d][n&3])
    short* aob = V4  + 786432;                   // 786432

    pack_in<<<512, 256, 0, stream>>>(x, Wqkv, Wo, xb, wqT, woT);
    {
        dim3 grid(12, 24);
        gemm1_qkv<<<grid, 256, 0, stream>>>(xb, wqT, Qb, Kb, V4);
    }
    attn_mfma<<<1536, 256, 0, stream>>>(Qb, Kb, V4, aob);
    {
        dim3 grid(4, 24);
        gemm2_out<<<grid, 256, 0, stream>>>(aob, woT, bo, out);
    }
}

// Round 5
// 45.003 us; speedup vs baseline: 10.8772x; 1.0546x over previous
//
#include <hip/hip_runtime.h>
#include <hip/hip_bf16.h>

// Problem constants (LightConeAttention): B=2, T=6, H=16, W=16, C=256, NUM_HEADS=8
#define BB   2
#define TT   6
#define HH   16
#define WW   16
#define CC   256
#define NH   8
#define HD   32
#define NN   (TT*HH*WW)      // 1536
#define BN   (BB*NN)         // 3072
#define SCALE 0.17677669529663687f  // 1/sqrt(32)

typedef __attribute__((ext_vector_type(8))) short bf16x8;
typedef __attribute__((ext_vector_type(4))) short bf16x4;
typedef __attribute__((ext_vector_type(4))) float f32x4;
typedef __attribute__((ext_vector_type(16))) float f32x16;

static __device__ inline short f2b(float x) {
    __hip_bfloat16 h = __float2bfloat16(x);
    return __builtin_bit_cast(short, h);
}

// ---------------------------------------------------------------------------
// Pack inputs to bf16: x -> xb [3072][256]; Wqkv -> WqkvT [768][256]; Wo -> WoT.
// ---------------------------------------------------------------------------
__global__ __launch_bounds__(256) void pack_in(const float* __restrict__ x,
                                               const float* __restrict__ Wqkv,
                                               const float* __restrict__ Wo,
                                               short* __restrict__ xb,
                                               short* __restrict__ wqT,
                                               short* __restrict__ woT) {
    const int bid = blockIdx.x;
    if (bid < 384) {
        int i = (bid * 256 + threadIdx.x) * 8;
        short t[8];
        #pragma unroll
        for (int j = 0; j < 8; ++j) t[j] = f2b(x[i + j]);
        *(bf16x8*)(xb + i) = *(bf16x8*)t;
    } else if (bid < 480) {                // WqkvT[n][k] = Wqkv[k][n]
        int idx = (bid - 384) * 256 + threadIdx.x;
        int k0 = (idx & 31) * 8;
        int n  = idx >> 5;
        short t[8];
        #pragma unroll
        for (int j = 0; j < 8; ++j) t[j] = f2b(Wqkv[(size_t)(k0 + j) * 768 + n]);
        *(bf16x8*)(wqT + (size_t)n * 256 + k0) = *(bf16x8*)t;
    } else {                               // WoT[n][k] = Wo[k][n]
        int idx = (bid - 480) * 256 + threadIdx.x;
        int k0 = (idx & 31) * 8;
        int n  = idx >> 5;
        short t[8];
        #pragma unroll
        for (int j = 0; j < 8; ++j) t[j] = f2b(Wo[(size_t)(k0 + j) * 256 + n]);
        *(bf16x8*)(woT + (size_t)n * 256 + k0) = *(bf16x8*)t;
    }
}

// ---------------------------------------------------------------------------
// GEMM1 (QKV projection), bf16 MFMA, no LDS. Epilogue scatters to attention
// layouts: Q (pre-scaled by SCALE) and K -> [bh][n][32];
// V -> VT32 [bh][kt=n>>5][d=32][k_local=n&31] (packed bf16x4 stores).
// grid (12, 24), block 256.
// ---------------------------------------------------------------------------
__global__ __launch_bounds__(256) void gemm1_qkv(const short* __restrict__ xb,
                                                 const short* __restrict__ wqT,
                                                 short* __restrict__ Qb,
                                                 short* __restrict__ Kb,
                                                 short* __restrict__ VT) {
    const int w = threadIdx.x >> 6, lane = threadIdx.x & 63;
    const int g = lane >> 4, c16 = lane & 15;
    const int mw = blockIdx.y * 128 + w * 32;
    const int n0 = blockIdx.x * 64;
    f32x4 acc[2][4] = {};
    #pragma unroll
    for (int ks = 0; ks < 8; ++ks) {
        const int k0 = ks * 32;
        bf16x8 a0 = *(const bf16x8*)(xb + (size_t)(mw + c16) * 256 + k0 + g * 8);
        bf16x8 a1 = *(const bf16x8*)(xb + (size_t)(mw + 16 + c16) * 256 + k0 + g * 8);
        #pragma unroll
        for (int ni = 0; ni < 4; ++ni) {
            bf16x8 bfr = *(const bf16x8*)(wqT + (size_t)(n0 + ni * 16 + c16) * 256 + k0 + g * 8);
            acc[0][ni] = __builtin_amdgcn_mfma_f32_16x16x32_bf16(a0, bfr, acc[0][ni], 0, 0, 0);
            acc[1][ni] = __builtin_amdgcn_mfma_f32_16x16x32_bf16(a1, bfr, acc[1][ni], 0, 0, 0);
        }
    }
    const int sec = blockIdx.x >> 2;       // 0:Q 1:K 2:V (uniform per block)
    #pragma unroll
    for (int mi = 0; mi < 2; ++mi) {
        const int brow = mw + mi * 16;
        const int b = brow >= NN;
        const int nbase = brow - b * NN;   // multiple of 16
        #pragma unroll
        for (int ni = 0; ni < 4; ++ni) {
            const int col = n0 + ni * 16;
            const int h  = (col >> 5) & 7;
            const int d0 = col & 31;       // 0 or 16
            const int bh = b * 8 + h;
            if (sec == 2) {
                short t4[4];
                #pragma unroll
                for (int r = 0; r < 4; ++r) t4[r] = f2b(acc[mi][ni][r]);
                const int kt  = nbase >> 5;
                const int klo = (nbase & 16) + 4 * g;
                size_t off = ((size_t)((bh * 48 + kt) * 32) + d0 + c16) * 32 + klo;
                *(bf16x4*)(VT + off) = *(bf16x4*)t4;
            } else {
                short* dst = (sec == 0) ? Qb : Kb;
                const float sc = (sec == 0) ? SCALE : 1.f;
                #pragma unroll
                for (int r = 0; r < 4; ++r)
                    dst[((size_t)bh * NN + nbase + 4 * g + r) * 32 + d0 + c16] =
                        f2b(acc[mi][ni][r] * sc);
            }
        }
    }
}

// ---------------------------------------------------------------------------
// 32x32 MFMA light-cone attention. One block (4 waves) per (bh, hq, tq-pair).
// Query tile = 32 queries: q<16 -> tq_a, q>=16 -> tq_b (same hq, w = q&15).
// Key tile = 32 keys: (tk, hk2) covering hk = 2*hk2, 2*hk2+1.
// Swapped QK^T: S^T = mfma_32x32x16(K,Q) twice (d halves). Lane (gb=lane>>5,
// q=lane&31) holds S[k_local=(r&3)+8*(r>>2)+4gb][q], r=0..15.
// P -> PV B-fragment via 8x v_cvt_pk_bf16_f32 + 4x v_permlane32_swap_b32.
// O^T += mfma_32x32x16(V^T, P) twice. Explicit next-tile prefetch.
// ---------------------------------------------------------------------------
__global__ __launch_bounds__(256) void attn_mfma32(const short* __restrict__ Qb,
                                                   const short* __restrict__ Kb,
                                                   const short* __restrict__ VT,
                                                   short* __restrict__ aob) {
    const int w    = threadIdx.x >> 6;
    const int lane = threadIdx.x & 63;
    const int l31  = lane & 31;
    const int gb   = lane >> 5;
    const int wq   = lane & 15;
    const int qh   = (lane >> 4) & 1;      // 0: tq_a query half, 1: tq_b
    const int wid  = blockIdx.x;           // 0..767
    const int qt = wid % 48, bh = wid / 48;
    const int tqp = qt >> 4, hq = qt & 15;
    const int tq_a = 2 * tqp, tq_b = tq_a + 1;

    // Q fragments: B[k=d][col=q]; lane q=l31, d = 8gb+i (lo) / 16+8gb+i (hi)
    const int tq_l = qh ? tq_b : tq_a;
    const int qn   = tq_l * 256 + hq * 16 + wq;
    const short* QBH = Qb + (size_t)bh * NN * 32;
    const bf16x8 qf0 = *(const bf16x8*)(QBH + (size_t)qn * 32 + 8 * gb);
    const bf16x8 qf1 = *(const bf16x8*)(QBH + (size_t)qn * 32 + 16 + 8 * gb);

    // |wk - wq| per r&7 (static): k_local&15 = (i&3) + 8*(i>>2) + 4gb
    int dwv[8];
    #pragma unroll
    for (int i = 0; i < 8; ++i) {
        int kl = (i & 3) + 8 * (i >> 2) + 4 * gb;
        int d = kl - wq; dwv[i] = d < 0 ? -d : d;
    }

    // enumerate visible 32-key tiles using rt_b (superset of rt_a windows)
    const int tqm_a = tq_a ? tq_a : 1;
    int ntiles = 0;
    int cst[6], h20[6], rtav[6], rtbv[6];
    #pragma unroll
    for (int tk = 0; tk < 6; ++tk) {
        int rb = 1 + (15 * (tq_b - tk)) / tq_b;
        int ra = (tk <= tq_a) ? (1 + (15 * (tq_a - tk)) / tqm_a) : -1;
        int lo = hq - rb; lo = lo < 0 ? 0 : lo;
        int hi = hq + rb; hi = hi > 15 ? 15 : hi;
        int c  = (tk <= tq_b) ? ((hi >> 1) - (lo >> 1) + 1) : 0;
        cst[tk] = ntiles; h20[tk] = lo >> 1; rtav[tk] = ra; rtbv[tk] = rb;
        ntiles += c;
    }

    __shared__ int desc[64];
    if (w == 0) {
        const int t = lane;
        int dsc = 255;                      // sentinel
        if (t < ntiles) {
            int sel = 0;
            #pragma unroll
            for (int tk = 1; tk < 6; ++tk)
                if (tk <= tq_b && t >= cst[tk]) sel = tk;
            const int hk2 = h20[sel] + (t - cst[sel]);
            dsc = ((sel * 256 + hk2 * 32) << 16) | ((rtav[sel] & 255) << 8) | (rtbv[sel] & 255);
        }
        if (t < 64) desc[t] = dsc;
    }
    __syncthreads();

    const short* KBH = Kb + (size_t)bh * NN * 32;
    const short* VBH = VT + (size_t)bh * 48 * 32 * 32;

    f32x16 acc, zf16;
    #pragma unroll
    for (int r = 0; r < 16; ++r) { acc[r] = 0.f; zf16[r] = 0.f; }
    float m_run = -1e4f, l_run = 0.f;      // -1e4: fully-masked lanes keep p==0

    int pi = w;
    int dc = 0;
    bf16x8 kf0c = {}, kf1c = {}, vf0c = {}, vf1c = {};
    if (pi < ntiles) {
        dc = desc[pi];
        const int kb = dc >> 16;
        kf0c = *(const bf16x8*)(KBH + (size_t)(kb + l31) * 32 + 8 * gb);
        kf1c = *(const bf16x8*)(KBH + (size_t)(kb + l31) * 32 + 16 + 8 * gb);
        vf0c = *(const bf16x8*)(VBH + (size_t)((kb >> 5) * 32 + l31) * 32 + 8 * gb);
        vf1c = *(const bf16x8*)(VBH + (size_t)((kb >> 5) * 32 + l31) * 32 + 16 + 8 * gb);
    }
    while (pi < ntiles) {
        // prefetch next tile (wave-uniform index, clamped)
        const int pn = pi + 4;
        const int pc = pn < ntiles ? pn : pi;
        const int dn = desc[pc];
        const int kbn = dn >> 16;
        const bf16x8 kf0n = *(const bf16x8*)(KBH + (size_t)(kbn + l31) * 32 + 8 * gb);
        const bf16x8 kf1n = *(const bf16x8*)(KBH + (size_t)(kbn + l31) * 32 + 16 + 8 * gb);
        const bf16x8 vf0n = *(const bf16x8*)(VBH + (size_t)((kbn >> 5) * 32 + l31) * 32 + 8 * gb);
        const bf16x8 vf1n = *(const bf16x8*)(VBH + (size_t)((kbn >> 5) * 32 + l31) * 32 + 16 + 8 * gb);

        // decode current
        const int rta = (dc << 16) >> 24;
        const int rtb = (dc << 24) >> 24;
        const int rt_l = qh ? rtb : rta;
        const int hk2 = (dc >> 21) & 7;    // (kb>>5)&7
        const int t0 = 2 * hk2 - hq;
        const int dh0 = t0 < 0 ? -t0 : t0;
        const int t1 = t0 + 1;
        const int dh1 = t1 < 0 ? -t1 : t1;
        const bool A0 = dh0 <= rt_l, A1 = dh1 <= rt_l;
        bool dok[8];
        #pragma unroll
        for (int i = 0; i < 8; ++i) dok[i] = dwv[i] <= rt_l;

        // S^T over d=32 (two chained MFMAs)
        f32x16 s = __builtin_amdgcn_mfma_f32_32x32x16_bf16(kf0c, qf0, zf16, 0, 0, 0);
        s = __builtin_amdgcn_mfma_f32_32x32x16_bf16(kf1c, qf1, s, 0, 0, 0);

        float e[16];
        #pragma unroll
        for (int r = 0; r < 16; ++r) {
            const bool ok = (r < 8 ? A0 : A1) && dok[r & 7];
            e[r] = ok ? s[r] : -1e30f;
        }
        float tmax = fmaxf(
            fmaxf(fmaxf(fmaxf(e[0], e[1]), fmaxf(e[2], e[3])),
                  fmaxf(fmaxf(e[4], e[5]), fmaxf(e[6], e[7]))),
            fmaxf(fmaxf(fmaxf(e[8], e[9]), fmaxf(e[10], e[11])),
                  fmaxf(fmaxf(e[12], e[13]), fmaxf(e[14], e[15]))));
        tmax = fmaxf(tmax, __shfl_xor(tmax, 32));

        if (!__all(tmax <= m_run)) {       // defer-rescale (wave-uniform)
            const float mn   = fmaxf(m_run, tmax);
            const float corr = __expf(m_run - mn);
            l_run *= corr;
            #pragma unroll
            for (int r = 0; r < 16; ++r) acc[r] *= corr;
            m_run = mn;
        }
        float p[16];
        #pragma unroll
        for (int r = 0; r < 16; ++r) p[r] = __expf(e[r] - m_run);
        float ps = (((p[0] + p[1]) + (p[2] + p[3])) + ((p[4] + p[5]) + (p[6] + p[7])))
                 + (((p[8] + p[9]) + (p[10] + p[11])) + ((p[12] + p[13]) + (p[14] + p[15])));
        ps += __shfl_xor(ps, 32);
        l_run += ps;

        // P -> PV B-fragment: 8 cvt_pk + 4 permlane32_swap
        unsigned u[8];
        #pragma unroll
        for (int j = 0; j < 8; ++j)
            asm("v_cvt_pk_bf16_f32 %0, %1, %2" : "=v"(u[j]) : "v"(p[2 * j]), "v"(p[2 * j + 1]));
        asm volatile("v_permlane32_swap_b32 %0, %1" : "+v"(u[0]), "+v"(u[2]));
        asm volatile("v_permlane32_swap_b32 %0, %1" : "+v"(u[1]), "+v"(u[3]));
        asm volatile("v_permlane32_swap_b32 %0, %1" : "+v"(u[4]), "+v"(u[6]));
        asm volatile("v_permlane32_swap_b32 %0, %1" : "+v"(u[5]), "+v"(u[7]));
        const int4 b1i = { (int)u[0], (int)u[1], (int)u[2], (int)u[3] };
        const int4 b2i = { (int)u[4], (int)u[5], (int)u[6], (int)u[7] };
        const bf16x8 pb1 = __builtin_bit_cast(bf16x8, b1i);
        const bf16x8 pb2 = __builtin_bit_cast(bf16x8, b2i);

        acc = __builtin_amdgcn_mfma_f32_32x32x16_bf16(vf0c, pb1, acc, 0, 0, 0);
        acc = __builtin_amdgcn_mfma_f32_32x32x16_bf16(vf1c, pb2, acc, 0, 0, 0);

        pi = pn; dc = dn;
        kf0c = kf0n; kf1c = kf1n; vf0c = vf0n; vf1c = vf1n;
    }

    // 4-way online-softmax merge via LDS
    __shared__ float sm_m[4][32];
    __shared__ float sm_l[4][32];
    __shared__ float sm_acc[4][64][17];
    if (gb == 0) { sm_m[w][l31] = m_run; sm_l[w][l31] = l_run; }
    #pragma unroll
    for (int r = 0; r < 16; ++r) sm_acc[w][lane][r] = acc[r];
    __syncthreads();
    if (w == 0) {
        const float m0 = sm_m[0][l31], m1 = sm_m[1][l31];
        const float m2 = sm_m[2][l31], m3 = sm_m[3][l31];
        const float mm = fmaxf(fmaxf(m0, m1), fmaxf(m2, m3));
        const float c0 = __expf(m0 - mm), c1 = __expf(m1 - mm);
        const float c2 = __expf(m2 - mm), c3 = __expf(m3 - mm);
        const float lt = sm_l[0][l31] * c0 + sm_l[1][l31] * c1
                       + sm_l[2][l31] * c2 + sm_l[3][l31] * c3;
        const float inv = 1.f / lt;
        short* op = aob + ((size_t)(bh >> 3) * NN + qn) * CC + (bh & 7) * 32;
        #pragma unroll
        for (int j = 0; j < 4; ++j) {       // d = 8j + 4gb + s
            short t4[4];
            #pragma unroll
            for (int s2 = 0; s2 < 4; ++s2) {
                const int r = 4 * j + s2;
                const float a = sm_acc[0][lane][r] * c0 + sm_acc[1][lane][r] * c1
                              + sm_acc[2][lane][r] * c2 + sm_acc[3][lane][r] * c3;
                t4[s2] = f2b(a * inv);
            }
            *(bf16x4*)(op + 8 * j + 4 * gb) = *(bf16x4*)t4;
        }
    }
}

// ---------------------------------------------------------------------------
// GEMM2 (output projection + bias), bf16 MFMA, fp32 out. grid (4, 24).
// ---------------------------------------------------------------------------
__global__ __launch_bounds__(256) void gemm2_out(const short* __restrict__ aob,
                                                 const short* __restrict__ woT,
                                                 const float* __restrict__ bias,
                                                 float* __restrict__ out) {
    const int w = threadIdx.x >> 6, lane = threadIdx.x & 63;
    const int g = lane >> 4, c16 = lane & 15;
    const int mw = blockIdx.y * 128 + w * 32;
    const int n0 = blockIdx.x * 64;
    f32x4 acc[2][4] = {};
    #pragma unroll
    for (int ks = 0; ks < 8; ++ks) {
        const int k0 = ks * 32;
        bf16x8 a0 = *(const bf16x8*)(aob + (size_t)(mw + c16) * 256 + k0 + g * 8);
        bf16x8 a1 = *(const bf16x8*)(aob + (size_t)(mw + 16 + c16) * 256 + k0 + g * 8);
        #pragma unroll
        for (int ni = 0; ni < 4; ++ni) {
            bf16x8 bfr = *(const bf16x8*)(woT + (size_t)(n0 + ni * 16 + c16) * 256 + k0 + g * 8);
            acc[0][ni] = __builtin_amdgcn_mfma_f32_16x16x32_bf16(a0, bfr, acc[0][ni], 0, 0, 0);
            acc[1][ni] = __builtin_amdgcn_mfma_f32_16x16x32_bf16(a1, bfr, acc[1][ni], 0, 0, 0);
        }
    }
    #pragma unroll
    for (int mi = 0; mi < 2; ++mi) {
        #pragma unroll
        for (int ni = 0; ni < 4; ++ni) {
            const int col = n0 + ni * 16 + c16;
            const float bv = bias[col];
            #pragma unroll
            for (int r = 0; r < 4; ++r)
                out[(size_t)(mw + mi * 16 + 4 * g + r) * 256 + col] = acc[mi][ni][r] + bv;
        }
    }
}

// ---------------------------------------------------------------------------
extern "C" void kernel_launch(void* const* d_in, const int* in_sizes, int n_in,
                              void* d_out, int out_size, void* d_ws, size_t ws_size,
                              hipStream_t stream) {
    const float* x    = (const float*)d_in[0];
    const float* Wqkv = (const float*)d_in[1];
    const float* Wo   = (const float*)d_in[2];
    const float* bo   = (const float*)d_in[3];
    float* out = (float*)d_out;

    short* xb  = (short*)d_ws;                   // 786432
    short* wqT = xb  + 786432;                   // 196608
    short* woT = wqT + 196608;                   // 65536
    short* Qb  = woT + 65536;                    // 786432
    short* Kb  = Qb  + 786432;                   // 786432
    short* VT  = Kb  + 786432;                   // 786432 ([bh][kt][d][k32])
    short* aob = VT  + 786432;                   // 786432

    pack_in<<<512, 256, 0, stream>>>(x, Wqkv, Wo, xb, wqT, woT);
    {
        dim3 grid(12, 24);
        gemm1_qkv<<<grid, 256, 0, stream>>>(xb, wqT, Qb, Kb, VT);
    }
    attn_mfma32<<<768, 256, 0, stream>>>(Qb, Kb, VT, aob);
    {
        dim3 grid(4, 24);
        gemm2_out<<<grid, 256, 0, stream>>>(aob, woT, bo, out);
    }
}